// Round 13
// baseline (139.314 us; speedup 1.0000x reference)
//
#include <hip/hip_runtime.h>
#include <hip/hip_bf16.h>

#define N_NODES 4096
#define DMODEL  1024
#define NHEAD   16
#define HDIM    64
#define NOUT    3072   // concat Q|K|V output columns

typedef __attribute__((ext_vector_type(8))) short short8v;
typedef __attribute__((ext_vector_type(4))) float f32x4;
typedef __attribute__((ext_vector_type(16))) float f32x16;
typedef __attribute__((ext_vector_type(4))) unsigned short ushort4v;
typedef __attribute__((ext_vector_type(4))) unsigned int u32x4;

static __device__ __forceinline__ void gload_lds16(const void* g, void* l) {
  __builtin_amdgcn_global_load_lds((const __attribute__((address_space(1))) void*)g,
                                   (__attribute__((address_space(3))) void*)l, 16, 0, 0);
}

static __device__ __forceinline__ unsigned cvtpk(float a, float b) {
  unsigned r;
  asm("v_cvt_pk_bf16_f32 %0, %1, %2" : "=v"(r) : "v"(a), "v"(b));
  return r;
}

// ---------- pass 1 (fused): node_emb fp32->bf16  +  W transpose->bf16 ----------
__global__ void prep_kernel(const float* __restrict__ x, __hip_bfloat16* __restrict__ xb,
                            const float* __restrict__ Wq, const float* __restrict__ Wk,
                            const float* __restrict__ Wv, __hip_bfloat16* __restrict__ WT) {
  __shared__ float tile[32][33];
  const int bid = blockIdx.x;
  const int t = threadIdx.x;
  if (bid < 4096) {
    int i = bid * 256 + t;
    float4 v = ((const float4*)x)[i];
    union { ushort4v u; __hip_bfloat16 h[4]; } o;
    o.h[0] = __float2bfloat16(v.x);
    o.h[1] = __float2bfloat16(v.y);
    o.h[2] = __float2bfloat16(v.z);
    o.h[3] = __float2bfloat16(v.w);
    ((ushort4v*)xb)[i] = o.u;
  } else {
    int b2 = bid - 4096;
    int z = b2 >> 10, rem = b2 & 1023;
    int bx = rem & 31, by = rem >> 5;
    const float* W = z == 0 ? Wq : (z == 1 ? Wk : Wv);
    int o0 = bx * 32, i0 = by * 32;
    int tx = t & 7, ty = t >> 3;  // 8 x 32
    {
      float4 v = *(const float4*)&W[(size_t)(i0 + ty) * DMODEL + o0 + tx * 4];
      tile[ty][tx * 4 + 0] = v.x;
      tile[ty][tx * 4 + 1] = v.y;
      tile[ty][tx * 4 + 2] = v.z;
      tile[ty][tx * 4 + 3] = v.w;
    }
    __syncthreads();
    __hip_bfloat16* outp = WT + (size_t)z * DMODEL * DMODEL;
    union { ushort4v u; __hip_bfloat16 h[4]; } o;
#pragma unroll
    for (int c = 0; c < 4; ++c) o.h[c] = __float2bfloat16(tile[tx * 4 + c][ty]);
    *(ushort4v*)&outp[(size_t)(o0 + ty) * DMODEL + i0 + tx * 4] = o.u;
  }
}

// ---------- pass 2: fused QKV GEMM, 128x128x32, counted-vmcnt double-buffer ----------
__global__ __launch_bounds__(256, 2) void gemm_qkv_kernel(
    const __hip_bfloat16* __restrict__ X, const __hip_bfloat16* __restrict__ WT,
    const float* __restrict__ bq, const float* __restrict__ bk, const float* __restrict__ bv,
    __hip_bfloat16* __restrict__ Qo, __hip_bfloat16* __restrict__ Ko, __hip_bfloat16* __restrict__ Vt) {
  __shared__ __hip_bfloat16 As[2][128 * 32];
  __shared__ __hip_bfloat16 Bs[2][128 * 32];
  const int t = threadIdx.x;
  const int lane = t & 63;
  const int w = t >> 6, wr = w >> 1, wc = w & 1;
  const int bm = blockIdx.y, bn = blockIdx.x;

  f32x4 acc[4][4] = {};

  const int rowA = t >> 2;
  const int koff = (t & 3) * 8;
  const __hip_bfloat16* Ag0 = X + (size_t)(bm * 128 + rowA) * DMODEL + koff;
  const __hip_bfloat16* Ag1 = X + (size_t)(bm * 128 + 64 + rowA) * DMODEL + koff;
  const __hip_bfloat16* Bg0 = WT + (size_t)(bn * 128 + rowA) * DMODEL + koff;
  const __hip_bfloat16* Bg1 = WT + (size_t)(bn * 128 + 64 + rowA) * DMODEL + koff;

  auto stage = [&](int kt, int b) {
    gload_lds16(Ag0 + kt * 32, &As[b][t * 8]);
    gload_lds16(Ag1 + kt * 32, &As[b][(t + 256) * 8]);
    gload_lds16(Bg0 + kt * 32, &Bs[b][t * 8]);
    gload_lds16(Bg1 + kt * 32, &Bs[b][(t + 256) * 8]);
  };

  const int fr = lane & 15, fk = (lane >> 4) * 8;

  stage(0, 0);

  for (int kt = 0; kt < DMODEL / 32; ++kt) {
    const int cur = kt & 1;
    __builtin_amdgcn_s_barrier();
    if (kt + 1 < DMODEL / 32) {
      stage(kt + 1, cur ^ 1);
      asm volatile("s_waitcnt vmcnt(4)" ::: "memory");
    } else {
      asm volatile("s_waitcnt vmcnt(0)" ::: "memory");
    }
    __builtin_amdgcn_s_barrier();
    __builtin_amdgcn_sched_barrier(0);

    const short* As_s = (const short*)As[cur];
    const short* Bs_s = (const short*)Bs[cur];
    short8v a[4], b[4];
#pragma unroll
    for (int m = 0; m < 4; ++m)
      a[m] = *(const short8v*)&As_s[(wr * 64 + m * 16 + fr) * 32 + fk];
#pragma unroll
    for (int n = 0; n < 4; ++n)
      b[n] = *(const short8v*)&Bs_s[(wc * 64 + n * 16 + fr) * 32 + fk];
#pragma unroll
    for (int m = 0; m < 4; ++m)
#pragma unroll
      for (int n = 0; n < 4; ++n)
        acc[m][n] = __builtin_amdgcn_mfma_f32_16x16x32_bf16(a[m], b[n], acc[m][n], 0, 0, 0);
  }

  const int row0 = bm * 128 + wr * 64;
  const int col0 = bn * 128 + wc * 64;
  const int which = col0 >> 10;
  const float* bias = which == 0 ? bq : (which == 1 ? bk : bv);
  const float QSCALE = 0.18033688011112042f;  // 0.125 * log2(e)
#pragma unroll
  for (int m = 0; m < 4; ++m) {
#pragma unroll
    for (int n = 0; n < 4; ++n) {
#pragma unroll
      for (int i = 0; i < 4; ++i) {
        int r = row0 + m * 16 + (lane >> 4) * 4 + i;
        int c = col0 + n * 16 + (lane & 15);
        int oo = c & 1023;
        float v = acc[m][n][i] + bias[oo];
        if (which == 0) v *= QSCALE;
        int h = oo >> 6, d = oo & 63;
        __hip_bfloat16 hv = __float2bfloat16(v);
        if (which == 0)      Qo[((size_t)h << 18) + r * 64 + d] = hv;
        else if (which == 1) Ko[((size_t)h << 18) + r * 64 + d] = hv;
        else                 Vt[((size_t)h << 18) + d * 4096 + r] = hv;
      }
    }
  }
}

// ---------- pass 3: flash attention, 64 q/wave, kv-half-at-a-time compute ----------
// Register diet: process kv halves sequentially so only 2 f32x16 S-tiles are
// live (32 regs vs 64). Target: ArchVGPR+AccVGPR <= ~160 -> 3 waves/SIMD,
// making grid 768 (= exactly 3 blocks/CU, 3x48KB LDS = 144 <= 160) effective.
// sched_barrier between halves keeps the compiler from re-merging live ranges.
__global__ __launch_bounds__(256, 2) void attn64_kernel(
    const __hip_bfloat16* __restrict__ Q, const __hip_bfloat16* __restrict__ K,
    const __hip_bfloat16* __restrict__ Vt,
    __hip_bfloat16* __restrict__ Opart, float* __restrict__ lpart) {
  __shared__ __align__(16) short lds_k[3 * 64 * 64];
  __shared__ __align__(16) short lds_v[3 * 64 * 64];

  // 768 blocks; XCD-bijective (96/XCD = 2 heads' blocks L2-local)
  const int bid = blockIdx.x;
  const int lin = (bid & 7) * 96 + (bid >> 3);
  const int h = lin / 48;
  const int rem = lin % 48;
  const int qb = rem / 3, split = rem % 3;

  // KV tile ranges: 22/21/21
  const int kt0 = (split == 0) ? 0 : (22 + 21 * (split - 1));
  const int ktN = kt0 + ((split == 0) ? 22 : 21);

  const int t = threadIdx.x, lane = t & 63, w = t >> 6;
  const int lq = lane & 31, hi = lane >> 5;

  const short* Qh = (const short*)Q + ((size_t)h << 18);
  const short* Kh = (const short*)K + ((size_t)h << 18);
  const short* Vh = (const short*)Vt + ((size_t)h << 18);

  const int q0 = qb * 256 + w * 64;

  short8v qfA[4], qfB[4];
#pragma unroll
  for (int kk = 0; kk < 4; ++kk) {
    qfA[kk] = *(const short8v*)&Qh[(q0 + lq) * 64 + kk * 16 + hi * 8];
    qfB[kk] = *(const short8v*)&Qh[(q0 + 32 + lq) * 64 + kk * 16 + hi * 8];
  }

  // XOR-swizzled ds_read offsets for rows 0-31; rows 32-63 = +2048 elements
  // (folds into the ds_read 16-bit offset immediate).
  int off0[4];
#pragma unroll
  for (int kk = 0; kk < 4; ++kk)
    off0[kk] = lq * 64 + (((kk * 2 + hi) ^ (lq & 7)) * 8);

  auto stage = [&](int kt, int boff) {
#pragma unroll
    for (int i = 0; i < 2; ++i) {
      int c = w * 128 + i * 64 + lane;
      int row = c >> 3, ss = (c & 7) ^ (row & 7);
      gload_lds16(Kh + (size_t)(kt * 64 + row) * 64 + ss * 8, &lds_k[boff + c * 8]);
    }
#pragma unroll
    for (int i = 0; i < 2; ++i) {
      int c = w * 128 + i * 64 + lane;
      int row = c >> 3, ss = (c & 7) ^ (row & 7);
      gload_lds16(Vh + (size_t)row * 4096 + kt * 64 + ss * 8, &lds_v[boff + c * 8]);
    }
  };

  f32x16 oA0 = {}, oA1 = {}, oB0 = {}, oB1 = {};
  float lA_r = 0.f, lB_r = 0.f;

  // one kv-half: QK^T (8 MFMA) -> exp2+pack -> PV (8 MFMA). khalf in {0,1}.
  auto half = [&](const short* kp, const short* vp, int khalf) {
    const int ko = khalf * 2048;          // K rows +32
    const int pk0 = khalf * 2, pk1 = khalf * 2 + 1;  // pa/vb kv-slice indices
    f32x16 sA = {}, sB = {};
#pragma unroll
    for (int kk = 0; kk < 4; ++kk) {
      short8v ka = *(const short8v*)&kp[off0[kk] + ko];
      sA = __builtin_amdgcn_mfma_f32_32x32x16_bf16(ka, qfA[kk], sA, 0, 0, 0);
      sB = __builtin_amdgcn_mfma_f32_32x32x16_bf16(ka, qfB[kk], sB, 0, 0, 0);
    }
#pragma unroll
    for (int j = 0; j < 16; ++j) { sA[j] = __builtin_amdgcn_exp2f(sA[j]); lA_r += sA[j]; }
#pragma unroll
    for (int j = 0; j < 16; ++j) { sB[j] = __builtin_amdgcn_exp2f(sB[j]); lB_r += sB[j]; }
    short8v paA0, paA1, paB0, paB1;
    {
      unsigned a0 = cvtpk(sA[0], sA[1]), a1 = cvtpk(sA[2], sA[3]);
      unsigned b0 = cvtpk(sA[4], sA[5]), b1 = cvtpk(sA[6], sA[7]);
      asm volatile("v_permlane32_swap_b32 %0, %1" : "+v"(a0), "+v"(b0));
      asm volatile("v_permlane32_swap_b32 %0, %1" : "+v"(a1), "+v"(b1));
      u32x4 u = {a0, a1, b0, b1};
      paA0 = __builtin_bit_cast(short8v, u);
    }
    {
      unsigned a0 = cvtpk(sA[8], sA[9]), a1 = cvtpk(sA[10], sA[11]);
      unsigned b0 = cvtpk(sA[12], sA[13]), b1 = cvtpk(sA[14], sA[15]);
      asm volatile("v_permlane32_swap_b32 %0, %1" : "+v"(a0), "+v"(b0));
      asm volatile("v_permlane32_swap_b32 %0, %1" : "+v"(a1), "+v"(b1));
      u32x4 u = {a0, a1, b0, b1};
      paA1 = __builtin_bit_cast(short8v, u);
    }
    {
      unsigned a0 = cvtpk(sB[0], sB[1]), a1 = cvtpk(sB[2], sB[3]);
      unsigned b0 = cvtpk(sB[4], sB[5]), b1 = cvtpk(sB[6], sB[7]);
      asm volatile("v_permlane32_swap_b32 %0, %1" : "+v"(a0), "+v"(b0));
      asm volatile("v_permlane32_swap_b32 %0, %1" : "+v"(a1), "+v"(b1));
      u32x4 u = {a0, a1, b0, b1};
      paB0 = __builtin_bit_cast(short8v, u);
    }
    {
      unsigned a0 = cvtpk(sB[8], sB[9]), a1 = cvtpk(sB[10], sB[11]);
      unsigned b0 = cvtpk(sB[12], sB[13]), b1 = cvtpk(sB[14], sB[15]);
      asm volatile("v_permlane32_swap_b32 %0, %1" : "+v"(a0), "+v"(b0));
      asm volatile("v_permlane32_swap_b32 %0, %1" : "+v"(a1), "+v"(b1));
      u32x4 u = {a0, a1, b0, b1};
      paB1 = __builtin_bit_cast(short8v, u);
    }
    // PV for this kv-half: pa{0,1} pair with vb slices pk0,pk1; d-half = +2048
    {
      short8v vb;
      vb = *(const short8v*)&vp[off0[pk0]];
      oA0 = __builtin_amdgcn_mfma_f32_32x32x16_bf16(paA0, vb, oA0, 0, 0, 0);
      oB0 = __builtin_amdgcn_mfma_f32_32x32x16_bf16(paB0, vb, oB0, 0, 0, 0);
      vb = *(const short8v*)&vp[off0[pk0] + 2048];
      oA1 = __builtin_amdgcn_mfma_f32_32x32x16_bf16(paA0, vb, oA1, 0, 0, 0);
      oB1 = __builtin_amdgcn_mfma_f32_32x32x16_bf16(paB0, vb, oB1, 0, 0, 0);
      vb = *(const short8v*)&vp[off0[pk1]];
      oA0 = __builtin_amdgcn_mfma_f32_32x32x16_bf16(paA1, vb, oA0, 0, 0, 0);
      oB0 = __builtin_amdgcn_mfma_f32_32x32x16_bf16(paB1, vb, oB0, 0, 0, 0);
      vb = *(const short8v*)&vp[off0[pk1] + 2048];
      oA1 = __builtin_amdgcn_mfma_f32_32x32x16_bf16(paA1, vb, oA1, 0, 0, 0);
      oB1 = __builtin_amdgcn_mfma_f32_32x32x16_bf16(paB1, vb, oB1, 0, 0, 0);
    }
  };

  stage(kt0, 0);
  int bS = 4096, bC = 0;

  for (int kt = kt0; kt < ktN; ++kt) {
    if (kt + 1 < ktN) {
      stage(kt + 1, bS);
      asm volatile("s_waitcnt vmcnt(4)" ::: "memory");
    } else {
      asm volatile("s_waitcnt vmcnt(0)" ::: "memory");
    }
    __builtin_amdgcn_s_barrier();
    __builtin_amdgcn_sched_barrier(0);
    half(lds_k + bC, lds_v + bC, 0);
    __builtin_amdgcn_sched_barrier(0);  // keep S live-ranges of the two halves disjoint
    half(lds_k + bC, lds_v + bC, 1);
    bC = bS;
    bS = (bS == 8192) ? 0 : (bS + 4096);
  }

  // epilogue: unnormalized bf16 O partials + fp32 l partials
  {
    float lA = lA_r + __shfl_xor(lA_r, 32);
    float lB = lB_r + __shfl_xor(lB_r, 32);
    if (hi == 0) {
      lpart[((split * NHEAD + h) << 12) + q0 + lq] = lA;
      lpart[((split * NHEAD + h) << 12) + q0 + 32 + lq] = lB;
    }
    __hip_bfloat16* Op = Opart + (size_t)split * N_NODES * DMODEL;
#pragma unroll
    for (int r = 0; r < 16; ++r) {
      int ql = (r & 3) + 8 * (r >> 2) + 4 * hi;
      int qgA = q0 + ql, qgB = q0 + 32 + ql;
      Op[(size_t)qgA * DMODEL + (h << 6) + lq] = __float2bfloat16(oA0[r]);
      Op[(size_t)qgA * DMODEL + (h << 6) + 32 + lq] = __float2bfloat16(oA1[r]);
      Op[(size_t)qgB * DMODEL + (h << 6) + lq] = __float2bfloat16(oB0[r]);
      Op[(size_t)qgB * DMODEL + (h << 6) + 32 + lq] = __float2bfloat16(oB1[r]);
    }
  }
}

// ---------- pass 4: out = (ΣO_s) / (Σl_s), 3 bf16 partials ----------
__global__ void combine_kernel(const __hip_bfloat16* __restrict__ Opart,
                               const float* __restrict__ lpart,
                               float* __restrict__ out) {
  int idx = blockIdx.x * 256 + threadIdx.x;
  int n = idx >> 8;
  int c4 = idx & 255;
  int h = c4 >> 4;
  float l = 0.f;
#pragma unroll
  for (int s = 0; s < 3; ++s) l += lpart[((s * NHEAD + h) << 12) + n];
  float inv = 1.0f / l;
  f32x4 o = {};
#pragma unroll
  for (int s = 0; s < 3; ++s) {
    ushort4v a = ((const ushort4v*)(Opart + (size_t)s * N_NODES * DMODEL))[idx];
#pragma unroll
    for (int j = 0; j < 4; ++j)
      o[j] += __uint_as_float((unsigned)(unsigned short)a[j] << 16);
  }
  ((f32x4*)out)[idx] = o * inv;
}

// ---------- fallback (ws too small): single-pass 32q/wave ----------
__global__ __launch_bounds__(256, 2) void attn_single_kernel(
    const __hip_bfloat16* __restrict__ Q, const __hip_bfloat16* __restrict__ K,
    const __hip_bfloat16* __restrict__ Vt, float* __restrict__ out) {
  __shared__ __align__(16) short lds_k[2][64 * 64];
  __shared__ __align__(16) short lds_v[2][64 * 64];
  __shared__ float smc[4][32];
  const int bid = blockIdx.x;
  const int lin = (bid & 7) * 64 + (bid >> 3);
  const int h = lin >> 5, qb = lin & 31;
  const int t = threadIdx.x, lane = t & 63, w = t >> 6;
  const int lq = lane & 31, hi = lane >> 5;
  const short* Qh = (const short*)Q + ((size_t)h << 18);
  const short* Kh = (const short*)K + ((size_t)h << 18);
  const short* Vh = (const short*)Vt + ((size_t)h << 18);
  const int q0 = qb * 128 + w * 32;
  short8v qf[4];
#pragma unroll
  for (int kk = 0; kk < 4; ++kk)
    qf[kk] = *(const short8v*)&Qh[(q0 + lq) * 64 + kk * 16 + hi * 8];
  int off8[2][4];
#pragma unroll
  for (int half = 0; half < 2; ++half)
#pragma unroll
    for (int kk = 0; kk < 4; ++kk)
      off8[half][kk] = (half * 32 + lq) * 64 + (((kk * 2 + hi) ^ (lq & 7)) * 8);
  auto stage = [&](int kt, int b) {
#pragma unroll
    for (int i = 0; i < 2; ++i) {
      int c = w * 128 + i * 64 + lane;
      int row = c >> 3, ss = (c & 7) ^ (row & 7);
      gload_lds16(Kh + (size_t)(kt * 64 + row) * 64 + ss * 8, &lds_k[b][c * 8]);
    }
#pragma unroll
    for (int i = 0; i < 2; ++i) {
      int c = w * 128 + i * 64 + lane;
      int row = c >> 3, ss = (c & 7) ^ (row & 7);
      gload_lds16(Vh + (size_t)row * 4096 + kt * 64 + ss * 8, &lds_v[b][c * 8]);
    }
  };
  f32x16 o0 = {}, o1 = {};
  float l_r = 0.f;
  stage(0, 0);
  for (int kt = 0; kt < 64; ++kt) {
    const int cur = kt & 1;
    __builtin_amdgcn_s_barrier();
    if (kt + 1 < 64) {
      stage(kt + 1, cur ^ 1);
      asm volatile("s_waitcnt vmcnt(4)" ::: "memory");
    } else {
      asm volatile("s_waitcnt vmcnt(0)" ::: "memory");
    }
    __builtin_amdgcn_s_barrier();
    __builtin_amdgcn_sched_barrier(0);
    const short* kp = lds_k[cur];
    const short* vp = lds_v[cur];
    f32x16 s0 = {}, s1 = {};
#pragma unroll
    for (int kk = 0; kk < 4; ++kk) {
      short8v ka0 = *(const short8v*)&kp[off8[0][kk]];
      s0 = __builtin_amdgcn_mfma_f32_32x32x16_bf16(ka0, qf[kk], s0, 0, 0, 0);
      short8v ka1 = *(const short8v*)&kp[off8[1][kk]];
      s1 = __builtin_amdgcn_mfma_f32_32x32x16_bf16(ka1, qf[kk], s1, 0, 0, 0);
    }
#pragma unroll
    for (int j = 0; j < 16; ++j) { s0[j] = __builtin_amdgcn_exp2f(s0[j]); l_r += s0[j]; }
#pragma unroll
    for (int j = 0; j < 16; ++j) { s1[j] = __builtin_amdgcn_exp2f(s1[j]); l_r += s1[j]; }
    short8v pa[4];
#pragma unroll
    for (int half = 0; half < 2; ++half) {
      const f32x16& s = half ? s1 : s0;
#pragma unroll
      for (int g = 0; g < 2; ++g) {
        unsigned a0 = cvtpk(s[g * 8 + 0], s[g * 8 + 1]), a1 = cvtpk(s[g * 8 + 2], s[g * 8 + 3]);
        unsigned b0 = cvtpk(s[g * 8 + 4], s[g * 8 + 5]), b1 = cvtpk(s[g * 8 + 6], s[g * 8 + 7]);
        asm volatile("v_permlane32_swap_b32 %0, %1" : "+v"(a0), "+v"(b0));
        asm volatile("v_permlane32_swap_b32 %0, %1" : "+v"(a1), "+v"(b1));
        u32x4 u = {a0, a1, b0, b1};
        pa[half * 2 + g] = __builtin_bit_cast(short8v, u);
      }
    }
#pragma unroll
    for (int kk = 0; kk < 4; ++kk) {
      short8v vb0 = *(const short8v*)&vp[off8[0][kk]];
      o0 = __builtin_amdgcn_mfma_f32_32x32x16_bf16(pa[kk], vb0, o0, 0, 0, 0);
      short8v vb1 = *(const short8v*)&vp[off8[1][kk]];
      o1 = __builtin_amdgcn_mfma_f32_32x32x16_bf16(pa[kk], vb1, o1, 0, 0, 0);
    }
  }
  {
    float lt = l_r + __shfl_xor(l_r, 32);
    float inv = 1.0f / lt;
    if (lane < 32) smc[w][lq] = inv;
#pragma unroll
    for (int r = 0; r < 16; ++r) {
      int ql = (r & 3) + 8 * (r >> 2) + 4 * hi;
      float iv = smc[w][ql];
      int qg = q0 + ql;
      out[(size_t)qg * DMODEL + (h << 6) + lq] = o0[r] * iv;
      out[(size_t)qg * DMODEL + (h << 6) + 32 + lq] = o1[r] * iv;
    }
  }
}

extern "C" void kernel_launch(void* const* d_in, const int* in_sizes, int n_in,
                              void* d_out, int out_size, void* d_ws, size_t ws_size,
                              hipStream_t stream) {
  const float* node_emb = (const float*)d_in[0];
  const float* Wq = (const float*)d_in[1];
  const float* bq = (const float*)d_in[2];
  const float* Wk = (const float*)d_in[3];
  const float* bk = (const float*)d_in[4];
  const float* Wv = (const float*)d_in[5];
  const float* bv = (const float*)d_in[6];
  float* out = (float*)d_out;

  // ws layout: [Qb|Kb|Vtb live through attn][Xbf|WT dead after GEMM -> Opart/lpart overlay]
  const size_t HSZ = (size_t)NHEAD * N_NODES * HDIM;
  __hip_bfloat16* Qb  = (__hip_bfloat16*)d_ws;
  __hip_bfloat16* Kb  = Qb + HSZ;
  __hip_bfloat16* Vtb = Kb + HSZ;
  __hip_bfloat16* Xbf = Vtb + HSZ;
  __hip_bfloat16* WT  = Xbf + (size_t)N_NODES * DMODEL;

  __hip_bfloat16* Opart = Xbf;  // overlays Xbf/WT (dead after GEMM)
  float* lpart = (float*)(Opart + 3 * (size_t)N_NODES * DMODEL);

  const size_t split_bytes =
      (3 * HSZ + 3 * (size_t)N_NODES * DMODEL) * sizeof(__hip_bfloat16) +
      3 * (size_t)NHEAD * N_NODES * sizeof(float);
  const size_t base_bytes =
      (3 * HSZ + (size_t)N_NODES * DMODEL + (size_t)NOUT * DMODEL) * sizeof(__hip_bfloat16);
  const bool can_split = ws_size >= (split_bytes > base_bytes ? split_bytes : base_bytes);

  prep_kernel<<<4096 + 3072, 256, 0, stream>>>(node_emb, Xbf, Wq, Wk, Wv, WT);
  gemm_qkv_kernel<<<dim3(NOUT / 128, N_NODES / 128), 256, 0, stream>>>(
      Xbf, WT, bq, bk, bv, Qb, Kb, Vtb);

  if (can_split) {
    attn64_kernel<<<768, 256, 0, stream>>>(Qb, Kb, Vtb, Opart, lpart);
    combine_kernel<<<(N_NODES * DMODEL) / (256 * 4), 256, 0, stream>>>(Opart, lpart, out);
  } else {
    attn_single_kernel<<<512, 256, 0, stream>>>(Qb, Kb, Vtb, out);
  }
}

// Round 14
// 131.654 us; speedup vs baseline: 1.0582x; 1.0582x over previous
//
#include <hip/hip_runtime.h>
#include <hip/hip_bf16.h>

#define N_NODES 4096
#define DMODEL  1024
#define NHEAD   16
#define HDIM    64
#define NOUT    3072   // concat Q|K|V output columns

typedef __attribute__((ext_vector_type(8))) short short8v;
typedef __attribute__((ext_vector_type(4))) float f32x4;
typedef __attribute__((ext_vector_type(16))) float f32x16;
typedef __attribute__((ext_vector_type(4))) unsigned short ushort4v;
typedef __attribute__((ext_vector_type(4))) unsigned int u32x4;

static __device__ __forceinline__ void gload_lds16(const void* g, void* l) {
  __builtin_amdgcn_global_load_lds((const __attribute__((address_space(1))) void*)g,
                                   (__attribute__((address_space(3))) void*)l, 16, 0, 0);
}

static __device__ __forceinline__ unsigned cvtpk(float a, float b) {
  unsigned r;
  asm("v_cvt_pk_bf16_f32 %0, %1, %2" : "=v"(r) : "v"(a), "v"(b));
  return r;
}

// ---------- pass 1 (fused): node_emb fp32->bf16  +  W transpose->bf16 ----------
__global__ void prep_kernel(const float* __restrict__ x, __hip_bfloat16* __restrict__ xb,
                            const float* __restrict__ Wq, const float* __restrict__ Wk,
                            const float* __restrict__ Wv, __hip_bfloat16* __restrict__ WT) {
  __shared__ float tile[32][33];
  const int bid = blockIdx.x;
  const int t = threadIdx.x;
  if (bid < 4096) {
    int i = bid * 256 + t;
    float4 v = ((const float4*)x)[i];
    union { ushort4v u; __hip_bfloat16 h[4]; } o;
    o.h[0] = __float2bfloat16(v.x);
    o.h[1] = __float2bfloat16(v.y);
    o.h[2] = __float2bfloat16(v.z);
    o.h[3] = __float2bfloat16(v.w);
    ((ushort4v*)xb)[i] = o.u;
  } else {
    int b2 = bid - 4096;
    int z = b2 >> 10, rem = b2 & 1023;
    int bx = rem & 31, by = rem >> 5;
    const float* W = z == 0 ? Wq : (z == 1 ? Wk : Wv);
    int o0 = bx * 32, i0 = by * 32;
    int tx = t & 7, ty = t >> 3;  // 8 x 32
    {
      float4 v = *(const float4*)&W[(size_t)(i0 + ty) * DMODEL + o0 + tx * 4];
      tile[ty][tx * 4 + 0] = v.x;
      tile[ty][tx * 4 + 1] = v.y;
      tile[ty][tx * 4 + 2] = v.z;
      tile[ty][tx * 4 + 3] = v.w;
    }
    __syncthreads();
    __hip_bfloat16* outp = WT + (size_t)z * DMODEL * DMODEL;
    union { ushort4v u; __hip_bfloat16 h[4]; } o;
#pragma unroll
    for (int c = 0; c < 4; ++c) o.h[c] = __float2bfloat16(tile[tx * 4 + c][ty]);
    *(ushort4v*)&outp[(size_t)(o0 + ty) * DMODEL + i0 + tx * 4] = o.u;
  }
}

// ---------- pass 2: fused QKV GEMM, 128x128x32, counted-vmcnt double-buffer ----------
__global__ __launch_bounds__(256, 2) void gemm_qkv_kernel(
    const __hip_bfloat16* __restrict__ X, const __hip_bfloat16* __restrict__ WT,
    const float* __restrict__ bq, const float* __restrict__ bk, const float* __restrict__ bv,
    __hip_bfloat16* __restrict__ Qo, __hip_bfloat16* __restrict__ Ko, __hip_bfloat16* __restrict__ Vt) {
  __shared__ __hip_bfloat16 As[2][128 * 32];
  __shared__ __hip_bfloat16 Bs[2][128 * 32];
  const int t = threadIdx.x;
  const int lane = t & 63;
  const int w = t >> 6, wr = w >> 1, wc = w & 1;
  const int bm = blockIdx.y, bn = blockIdx.x;

  f32x4 acc[4][4] = {};

  const int rowA = t >> 2;
  const int koff = (t & 3) * 8;
  const __hip_bfloat16* Ag0 = X + (size_t)(bm * 128 + rowA) * DMODEL + koff;
  const __hip_bfloat16* Ag1 = X + (size_t)(bm * 128 + 64 + rowA) * DMODEL + koff;
  const __hip_bfloat16* Bg0 = WT + (size_t)(bn * 128 + rowA) * DMODEL + koff;
  const __hip_bfloat16* Bg1 = WT + (size_t)(bn * 128 + 64 + rowA) * DMODEL + koff;

  auto stage = [&](int kt, int b) {
    gload_lds16(Ag0 + kt * 32, &As[b][t * 8]);
    gload_lds16(Ag1 + kt * 32, &As[b][(t + 256) * 8]);
    gload_lds16(Bg0 + kt * 32, &Bs[b][t * 8]);
    gload_lds16(Bg1 + kt * 32, &Bs[b][(t + 256) * 8]);
  };

  const int fr = lane & 15, fk = (lane >> 4) * 8;

  stage(0, 0);

  for (int kt = 0; kt < DMODEL / 32; ++kt) {
    const int cur = kt & 1;
    __builtin_amdgcn_s_barrier();  // B1: all waves done reading buf cur^1
    if (kt + 1 < DMODEL / 32) {
      stage(kt + 1, cur ^ 1);
      asm volatile("s_waitcnt vmcnt(4)" ::: "memory");  // cur tile landed, next in flight
    } else {
      asm volatile("s_waitcnt vmcnt(0)" ::: "memory");
    }
    __builtin_amdgcn_s_barrier();  // B2: buf cur staged by all waves
    __builtin_amdgcn_sched_barrier(0);

    const short* As_s = (const short*)As[cur];
    const short* Bs_s = (const short*)Bs[cur];
    short8v a[4], b[4];
#pragma unroll
    for (int m = 0; m < 4; ++m)
      a[m] = *(const short8v*)&As_s[(wr * 64 + m * 16 + fr) * 32 + fk];
#pragma unroll
    for (int n = 0; n < 4; ++n)
      b[n] = *(const short8v*)&Bs_s[(wc * 64 + n * 16 + fr) * 32 + fk];
#pragma unroll
    for (int m = 0; m < 4; ++m)
#pragma unroll
      for (int n = 0; n < 4; ++n)
        acc[m][n] = __builtin_amdgcn_mfma_f32_16x16x32_bf16(a[m], b[n], acc[m][n], 0, 0, 0);
  }

  const int row0 = bm * 128 + wr * 64;
  const int col0 = bn * 128 + wc * 64;
  const int which = col0 >> 10;
  const float* bias = which == 0 ? bq : (which == 1 ? bk : bv);
  const float QSCALE = 0.18033688011112042f;  // 0.125 * log2(e)
#pragma unroll
  for (int m = 0; m < 4; ++m) {
#pragma unroll
    for (int n = 0; n < 4; ++n) {
#pragma unroll
      for (int i = 0; i < 4; ++i) {
        int r = row0 + m * 16 + (lane >> 4) * 4 + i;
        int c = col0 + n * 16 + (lane & 15);
        int oo = c & 1023;
        float v = acc[m][n][i] + bias[oo];
        if (which == 0) v *= QSCALE;
        int h = oo >> 6, d = oo & 63;
        __hip_bfloat16 hv = __float2bfloat16(v);
        if (which == 0)      Qo[((size_t)h << 18) + r * 64 + d] = hv;
        else if (which == 1) Ko[((size_t)h << 18) + r * 64 + d] = hv;
        else                 Vt[((size_t)h << 18) + d * 4096 + r] = hv;
      }
    }
  }
}

// ---------- pass 3: flash attention, 64 q-rows/wave, 2-tile barrier intervals ----------
// (R11 configuration — session-best attn at 84.2-84.9 us; structural local
// optimum: 2 waves/SIMD unified-register-bound, serial QK^T->softmax->PV chain)
__global__ __launch_bounds__(256, 2) void attn64_kernel(
    const __hip_bfloat16* __restrict__ Q, const __hip_bfloat16* __restrict__ K,
    const __hip_bfloat16* __restrict__ Vt,
    __hip_bfloat16* __restrict__ Opart, float* __restrict__ lpart) {
  __shared__ __align__(16) short lds_k[2][2][64 * 64];
  __shared__ __align__(16) short lds_v[2][2][64 * 64];

  const int bid = blockIdx.x;
  const int lin = (bid & 7) * 64 + (bid >> 3);
  const int h = lin >> 5, qb = (lin & 31) >> 1, split = lin & 1;

  const int t = threadIdx.x, lane = t & 63, w = t >> 6;
  const int lq = lane & 31, hi = lane >> 5;

  const short* Qh = (const short*)Q + ((size_t)h << 18);
  const short* Kh = (const short*)K + ((size_t)h << 18);
  const short* Vh = (const short*)Vt + ((size_t)h << 18);

  const int q0 = qb * 256 + w * 64;

  short8v qfA[4], qfB[4];
#pragma unroll
  for (int kk = 0; kk < 4; ++kk) {
    qfA[kk] = *(const short8v*)&Qh[(q0 + lq) * 64 + kk * 16 + hi * 8];
    qfB[kk] = *(const short8v*)&Qh[(q0 + 32 + lq) * 64 + kk * 16 + hi * 8];
  }

  int off8[2][4];
#pragma unroll
  for (int half = 0; half < 2; ++half)
#pragma unroll
    for (int kk = 0; kk < 4; ++kk)
      off8[half][kk] = (half * 32 + lq) * 64 + (((kk * 2 + hi) ^ (lq & 7)) * 8);

  auto stage = [&](int kt, int p, int s) {
#pragma unroll
    for (int i = 0; i < 2; ++i) {
      int c = w * 128 + i * 64 + lane;
      int row = c >> 3, ss = (c & 7) ^ (row & 7);
      gload_lds16(Kh + (size_t)(kt * 64 + row) * 64 + ss * 8, &lds_k[p][s][c * 8]);
    }
#pragma unroll
    for (int i = 0; i < 2; ++i) {
      int c = w * 128 + i * 64 + lane;
      int row = c >> 3, ss = (c & 7) ^ (row & 7);
      gload_lds16(Vh + (size_t)row * 4096 + kt * 64 + ss * 8, &lds_v[p][s][c * 8]);
    }
  };

  f32x16 oA0 = {}, oA1 = {}, oB0 = {}, oB1 = {};
  float lA_r = 0.f, lB_r = 0.f;

  auto compute = [&](const short* kp, const short* vp) {
    f32x16 sA0 = {}, sA1 = {}, sB0 = {}, sB1 = {};
#pragma unroll
    for (int kk = 0; kk < 4; ++kk) {
      short8v ka0 = *(const short8v*)&kp[off8[0][kk]];
      sA0 = __builtin_amdgcn_mfma_f32_32x32x16_bf16(ka0, qfA[kk], sA0, 0, 0, 0);
      sB0 = __builtin_amdgcn_mfma_f32_32x32x16_bf16(ka0, qfB[kk], sB0, 0, 0, 0);
      short8v ka1 = *(const short8v*)&kp[off8[1][kk]];
      sA1 = __builtin_amdgcn_mfma_f32_32x32x16_bf16(ka1, qfA[kk], sA1, 0, 0, 0);
      sB1 = __builtin_amdgcn_mfma_f32_32x32x16_bf16(ka1, qfB[kk], sB1, 0, 0, 0);
    }
    short8v paA[4], paB[4];
#pragma unroll
    for (int j = 0; j < 16; ++j) { sA0[j] = __builtin_amdgcn_exp2f(sA0[j]); lA_r += sA0[j]; }
#pragma unroll
    for (int j = 0; j < 16; ++j) { sA1[j] = __builtin_amdgcn_exp2f(sA1[j]); lA_r += sA1[j]; }
#pragma unroll
    for (int half = 0; half < 2; ++half) {
      const f32x16& s = half ? sA1 : sA0;
#pragma unroll
      for (int g = 0; g < 2; ++g) {
        unsigned a0 = cvtpk(s[g * 8 + 0], s[g * 8 + 1]), a1 = cvtpk(s[g * 8 + 2], s[g * 8 + 3]);
        unsigned b0 = cvtpk(s[g * 8 + 4], s[g * 8 + 5]), b1 = cvtpk(s[g * 8 + 6], s[g * 8 + 7]);
        asm volatile("v_permlane32_swap_b32 %0, %1" : "+v"(a0), "+v"(b0));
        asm volatile("v_permlane32_swap_b32 %0, %1" : "+v"(a1), "+v"(b1));
        u32x4 u = {a0, a1, b0, b1};
        paA[half * 2 + g] = __builtin_bit_cast(short8v, u);
      }
    }
#pragma unroll
    for (int j = 0; j < 16; ++j) { sB0[j] = __builtin_amdgcn_exp2f(sB0[j]); lB_r += sB0[j]; }
#pragma unroll
    for (int j = 0; j < 16; ++j) { sB1[j] = __builtin_amdgcn_exp2f(sB1[j]); lB_r += sB1[j]; }
#pragma unroll
    for (int half = 0; half < 2; ++half) {
      const f32x16& s = half ? sB1 : sB0;
#pragma unroll
      for (int g = 0; g < 2; ++g) {
        unsigned a0 = cvtpk(s[g * 8 + 0], s[g * 8 + 1]), a1 = cvtpk(s[g * 8 + 2], s[g * 8 + 3]);
        unsigned b0 = cvtpk(s[g * 8 + 4], s[g * 8 + 5]), b1 = cvtpk(s[g * 8 + 6], s[g * 8 + 7]);
        asm volatile("v_permlane32_swap_b32 %0, %1" : "+v"(a0), "+v"(b0));
        asm volatile("v_permlane32_swap_b32 %0, %1" : "+v"(a1), "+v"(b1));
        u32x4 u = {a0, a1, b0, b1};
        paB[half * 2 + g] = __builtin_bit_cast(short8v, u);
      }
    }
#pragma unroll
    for (int kk = 0; kk < 4; ++kk) {
      short8v vb0 = *(const short8v*)&vp[off8[0][kk]];
      oA0 = __builtin_amdgcn_mfma_f32_32x32x16_bf16(paA[kk], vb0, oA0, 0, 0, 0);
      oB0 = __builtin_amdgcn_mfma_f32_32x32x16_bf16(paB[kk], vb0, oB0, 0, 0, 0);
      short8v vb1 = *(const short8v*)&vp[off8[1][kk]];
      oA1 = __builtin_amdgcn_mfma_f32_32x32x16_bf16(paA[kk], vb1, oA1, 0, 0, 0);
      oB1 = __builtin_amdgcn_mfma_f32_32x32x16_bf16(paB[kk], vb1, oB1, 0, 0, 0);
    }
  };

  const int NT = 32;
  const int NIV = NT / 2;
  const int kt0 = split * NT;

  stage(kt0 + 0, 0, 0);
  stage(kt0 + 1, 0, 1);

  for (int iv = 0; iv < NIV; ++iv) {
    const int p = iv & 1;
    __builtin_amdgcn_s_barrier();
    if (iv + 1 < NIV) {
      stage(kt0 + 2 * iv + 2, p ^ 1, 0);
      stage(kt0 + 2 * iv + 3, p ^ 1, 1);
      asm volatile("s_waitcnt vmcnt(8)" ::: "memory");
    } else {
      asm volatile("s_waitcnt vmcnt(0)" ::: "memory");
    }
    __builtin_amdgcn_s_barrier();
    __builtin_amdgcn_sched_barrier(0);
    compute(lds_k[p][0], lds_v[p][0]);
    compute(lds_k[p][1], lds_v[p][1]);
  }

  {
    float lA = lA_r + __shfl_xor(lA_r, 32);
    float lB = lB_r + __shfl_xor(lB_r, 32);
    if (hi == 0) {
      lpart[((split * NHEAD + h) << 12) + q0 + lq] = lA;
      lpart[((split * NHEAD + h) << 12) + q0 + 32 + lq] = lB;
    }
    __hip_bfloat16* Op = Opart + (size_t)split * N_NODES * DMODEL;
#pragma unroll
    for (int r = 0; r < 16; ++r) {
      int ql = (r & 3) + 8 * (r >> 2) + 4 * hi;
      int qgA = q0 + ql, qgB = q0 + 32 + ql;
      Op[(size_t)qgA * DMODEL + (h << 6) + lq] = __float2bfloat16(oA0[r]);
      Op[(size_t)qgA * DMODEL + (h << 6) + 32 + lq] = __float2bfloat16(oA1[r]);
      Op[(size_t)qgB * DMODEL + (h << 6) + lq] = __float2bfloat16(oB0[r]);
      Op[(size_t)qgB * DMODEL + (h << 6) + 32 + lq] = __float2bfloat16(oB1[r]);
    }
  }
}

// ---------- pass 4: out = (O0 + O1) / (l0 + l1), bf16 partials ----------
__global__ void combine_kernel(const __hip_bfloat16* __restrict__ Opart,
                               const float* __restrict__ lpart,
                               float* __restrict__ out) {
  int idx = blockIdx.x * 256 + threadIdx.x;
  int n = idx >> 8;
  int c4 = idx & 255;
  int h = c4 >> 4;
  float l0 = lpart[(h << 12) + n];
  float l1 = lpart[(NHEAD << 12) + (h << 12) + n];
  float inv = 1.0f / (l0 + l1);
  ushort4v a = ((const ushort4v*)Opart)[idx];
  ushort4v b = ((const ushort4v*)(Opart + (size_t)N_NODES * DMODEL))[idx];
  f32x4 o;
#pragma unroll
  for (int j = 0; j < 4; ++j) {
    float fa = __uint_as_float((unsigned)(unsigned short)a[j] << 16);
    float fb = __uint_as_float((unsigned)(unsigned short)b[j] << 16);
    o[j] = (fa + fb) * inv;
  }
  ((f32x4*)out)[idx] = o;
}

// ---------- fallback (ws too small): single-pass 32q/wave ----------
__global__ __launch_bounds__(256, 2) void attn_single_kernel(
    const __hip_bfloat16* __restrict__ Q, const __hip_bfloat16* __restrict__ K,
    const __hip_bfloat16* __restrict__ Vt, float* __restrict__ out) {
  __shared__ __align__(16) short lds_k[2][64 * 64];
  __shared__ __align__(16) short lds_v[2][64 * 64];
  __shared__ float smc[4][32];
  const int bid = blockIdx.x;
  const int lin = (bid & 7) * 64 + (bid >> 3);
  const int h = lin >> 5, qb = lin & 31;
  const int t = threadIdx.x, lane = t & 63, w = t >> 6;
  const int lq = lane & 31, hi = lane >> 5;
  const short* Qh = (const short*)Q + ((size_t)h << 18);
  const short* Kh = (const short*)K + ((size_t)h << 18);
  const short* Vh = (const short*)Vt + ((size_t)h << 18);
  const int q0 = qb * 128 + w * 32;
  short8v qf[4];
#pragma unroll
  for (int kk = 0; kk < 4; ++kk)
    qf[kk] = *(const short8v*)&Qh[(q0 + lq) * 64 + kk * 16 + hi * 8];
  int off8[2][4];
#pragma unroll
  for (int half = 0; half < 2; ++half)
#pragma unroll
    for (int kk = 0; kk < 4; ++kk)
      off8[half][kk] = (half * 32 + lq) * 64 + (((kk * 2 + hi) ^ (lq & 7)) * 8);
  auto stage = [&](int kt, int b) {
#pragma unroll
    for (int i = 0; i < 2; ++i) {
      int c = w * 128 + i * 64 + lane;
      int row = c >> 3, ss = (c & 7) ^ (row & 7);
      gload_lds16(Kh + (size_t)(kt * 64 + row) * 64 + ss * 8, &lds_k[b][c * 8]);
    }
#pragma unroll
    for (int i = 0; i < 2; ++i) {
      int c = w * 128 + i * 64 + lane;
      int row = c >> 3, ss = (c & 7) ^ (row & 7);
      gload_lds16(Vh + (size_t)row * 4096 + kt * 64 + ss * 8, &lds_v[b][c * 8]);
    }
  };
  f32x16 o0 = {}, o1 = {};
  float l_r = 0.f;
  stage(0, 0);
  for (int kt = 0; kt < 64; ++kt) {
    const int cur = kt & 1;
    __builtin_amdgcn_s_barrier();
    if (kt + 1 < 64) {
      stage(kt + 1, cur ^ 1);
      asm volatile("s_waitcnt vmcnt(4)" ::: "memory");
    } else {
      asm volatile("s_waitcnt vmcnt(0)" ::: "memory");
    }
    __builtin_amdgcn_s_barrier();
    __builtin_amdgcn_sched_barrier(0);
    const short* kp = lds_k[cur];
    const short* vp = lds_v[cur];
    f32x16 s0 = {}, s1 = {};
#pragma unroll
    for (int kk = 0; kk < 4; ++kk) {
      short8v ka0 = *(const short8v*)&kp[off8[0][kk]];
      s0 = __builtin_amdgcn_mfma_f32_32x32x16_bf16(ka0, qf[kk], s0, 0, 0, 0);
      short8v ka1 = *(const short8v*)&kp[off8[1][kk]];
      s1 = __builtin_amdgcn_mfma_f32_32x32x16_bf16(ka1, qf[kk], s1, 0, 0, 0);
    }
#pragma unroll
    for (int j = 0; j < 16; ++j) { s0[j] = __builtin_amdgcn_exp2f(s0[j]); l_r += s0[j]; }
#pragma unroll
    for (int j = 0; j < 16; ++j) { s1[j] = __builtin_amdgcn_exp2f(s1[j]); l_r += s1[j]; }
    short8v pa[4];
#pragma unroll
    for (int half = 0; half < 2; ++half) {
      const f32x16& s = half ? s1 : s0;
#pragma unroll
      for (int g = 0; g < 2; ++g) {
        unsigned a0 = cvtpk(s[g * 8 + 0], s[g * 8 + 1]), a1 = cvtpk(s[g * 8 + 2], s[g * 8 + 3]);
        unsigned b0 = cvtpk(s[g * 8 + 4], s[g * 8 + 5]), b1 = cvtpk(s[g * 8 + 6], s[g * 8 + 7]);
        asm volatile("v_permlane32_swap_b32 %0, %1" : "+v"(a0), "+v"(b0));
        asm volatile("v_permlane32_swap_b32 %0, %1" : "+v"(a1), "+v"(b1));
        u32x4 u = {a0, a1, b0, b1};
        pa[half * 2 + g] = __builtin_bit_cast(short8v, u);
      }
    }
#pragma unroll
    for (int kk = 0; kk < 4; ++kk) {
      short8v vb0 = *(const short8v*)&vp[off8[0][kk]];
      o0 = __builtin_amdgcn_mfma_f32_32x32x16_bf16(pa[kk], vb0, o0, 0, 0, 0);
      short8v vb1 = *(const short8v*)&vp[off8[1][kk]];
      o1 = __builtin_amdgcn_mfma_f32_32x32x16_bf16(pa[kk], vb1, o1, 0, 0, 0);
    }
  }
  {
    float lt = l_r + __shfl_xor(l_r, 32);
    float inv = 1.0f / lt;
    if (lane < 32) smc[w][lq] = inv;
#pragma unroll
    for (int r = 0; r < 16; ++r) {
      int ql = (r & 3) + 8 * (r >> 2) + 4 * hi;
      float iv = smc[w][ql];
      int qg = q0 + ql;
      out[(size_t)qg * DMODEL + (h << 6) + lq] = o0[r] * iv;
      out[(size_t)qg * DMODEL + (h << 6) + 32 + lq] = o1[r] * iv;
    }
  }
}

extern "C" void kernel_launch(void* const* d_in, const int* in_sizes, int n_in,
                              void* d_out, int out_size, void* d_ws, size_t ws_size,
                              hipStream_t stream) {
  const float* node_emb = (const float*)d_in[0];
  const float* Wq = (const float*)d_in[1];
  const float* bq = (const float*)d_in[2];
  const float* Wk = (const float*)d_in[3];
  const float* bk = (const float*)d_in[4];
  const float* Wv = (const float*)d_in[5];
  const float* bv = (const float*)d_in[6];
  float* out = (float*)d_out;

  // ws layout: [Qb|Kb|Vtb live through attn][Xbf|WT dead after GEMM -> Opart/lpart overlay]
  const size_t HSZ = (size_t)NHEAD * N_NODES * HDIM;
  __hip_bfloat16* Qb  = (__hip_bfloat16*)d_ws;
  __hip_bfloat16* Kb  = Qb + HSZ;
  __hip_bfloat16* Vtb = Kb + HSZ;
  __hip_bfloat16* Xbf = Vtb + HSZ;
  __hip_bfloat16* WT  = Xbf + (size_t)N_NODES * DMODEL;

  __hip_bfloat16* Opart = Xbf;  // overlays Xbf/WT (dead after GEMM)
  float* lpart = (float*)(Opart + 2 * (size_t)N_NODES * DMODEL);

  const size_t split_bytes =
      (3 * HSZ + 2 * (size_t)N_NODES * DMODEL) * sizeof(__hip_bfloat16) +
      2 * (size_t)NHEAD * N_NODES * sizeof(float);
  const size_t base_bytes =
      (3 * HSZ + (size_t)N_NODES * DMODEL + (size_t)NOUT * DMODEL) * sizeof(__hip_bfloat16);
  const bool can_split = ws_size >= (split_bytes > base_bytes ? split_bytes : base_bytes);

  prep_kernel<<<4096 + 3072, 256, 0, stream>>>(node_emb, Xbf, Wq, Wk, Wv, WT);
  gemm_qkv_kernel<<<dim3(NOUT / 128, N_NODES / 128), 256, 0, stream>>>(
      Xbf, WT, bq, bk, bv, Qb, Kb, Vtb);

  if (can_split) {
    attn64_kernel<<<512, 256, 0, stream>>>(Qb, Kb, Vtb, Opart, lpart);
    combine_kernel<<<(N_NODES * DMODEL) / (256 * 4), 256, 0, stream>>>(Opart, lpart, out);
  } else {
    attn_single_kernel<<<512, 256, 0, stream>>>(Qb, Kb, Vtb, out);
  }
}